// Round 5
// baseline (521.881 us; speedup 1.0000x reference)
//
#include <hip/hip_runtime.h>
#include <math.h>

#define N_TOTAL 500000
#define P_NODES 21
#define KNEG    5
#define DDIM    128
#define BATCH   1024
#define N_PAIRS 185                      // window pairs
#define N_NEG   (N_PAIRS * KNEG)         // 925 per b
#define NNEG_TOT (N_PAIRS * BATCH * KNEG)  // 947200
#define NPOS_TOT (N_PAIRS * BATCH)         // 189440
#define C_ROWS  (BATCH * P_NODES)        // 21504 context rows

// --- binned layout ---
#define BROWS   64                       // table rows per bucket (32 KB)
#define NBUCKET ((N_TOTAL + BROWS - 1) / BROWS)   // 7813
#define CAP     224                      // record capacity per bucket (mean 121, 9σ margin)
#define C_BYTES ((size_t)C_ROWS * DDIM * 4)       // 11,010,048
#define CNT_OFF C_BYTES
#define REC_OFF (CNT_OFF + 32768)
#define WS_NEEDED (REC_OFF + (size_t)NBUCKET * CAP * 4)   // ~18.1 MB

struct Pairs { unsigned char pi[N_PAIRS]; unsigned char pj[N_PAIRS]; };

constexpr Pairs make_pairs() {
    Pairs p{};
    int n = 0;
    for (int i = 0; i < P_NODES; ++i) {
        int jlo = (i - KNEG > 0) ? i - KNEG : 0;
        int jhi = (i + KNEG < P_NODES) ? i + KNEG : P_NODES;
        for (int j = jlo; j < jhi; ++j) { p.pi[n] = (unsigned char)i; p.pj[n] = (unsigned char)j; ++n; }
    }
    return p;
}

__constant__ Pairs PAIRS = make_pairs();

__device__ __forceinline__ float lsig(float x) {
    return -__logf(1.f + __expf(-x));   // dots are tiny here; no overflow risk
}

__device__ __forceinline__ float dot4(float4 a, float4 b) {
    return fmaf(a.x, b.x, fmaf(a.y, b.y, fmaf(a.z, b.z, a.w * b.w)));
}

// ---- K0: materialize C[c_id = b*21 + i] = emb[path[b][i]] (11 MB, contiguous) ----
__global__ __launch_bounds__(256) void k_build_c(
    const float* __restrict__ emb, const int* __restrict__ path, float* __restrict__ C)
{
    int e   = blockIdx.x * 256 + threadIdx.x;       // over C_ROWS*128 = 2,752,512
    int cid = e >> 7;
    int col = e & 127;
    int b   = cid / P_NODES;
    int i   = cid - b * P_NODES;
    C[e] = emb[(size_t)path[b * P_NODES + i] * DDIM + col];
}

// ---- K1: bin neg tasks by table region ----
__global__ __launch_bounds__(256) void k_bin(
    const int* __restrict__ neg, int* __restrict__ cnt, unsigned* __restrict__ rec)
{
    int n = blockIdx.x * 256 + threadIdx.x;         // over 947200 exactly
    int p   = n / (BATCH * KNEG);
    int rem = n - p * (BATCH * KNEG);
    int b   = (int)(((unsigned)rem * 52429u) >> 18);  // rem/5, rem < 5120
    int idx = neg[n];
    int bucket = idx >> 6;
    int lr     = idx & (BROWS - 1);
    int cid    = b * P_NODES + PAIRS.pi[p];
    int slot = atomicAdd(&cnt[bucket], 1);
    if (slot < CAP)
        rec[(size_t)bucket * CAP + slot] = ((unsigned)cid << 6) | (unsigned)lr;
}

// ---- Kpos: 189440 positive dots, both rows from hot C ----
__global__ __launch_bounds__(256) void k_pos(
    const float* __restrict__ C, float* __restrict__ out)
{
    const int t  = threadIdx.x;
    const int m  = t & 3;
    const int gq = (blockIdx.x * 256 + t) >> 2;     // 47360 quads; 4 tasks each
    float acc = 0.f;
    #pragma unroll
    for (int s = gq; s < NPOS_TOT; s += 47360) {
        int p = s >> 10;                             // s = p*1024 + b
        int b = s & 1023;
        const float4* A = (const float4*)(C + ((size_t)b * P_NODES + PAIRS.pi[p]) * DDIM);
        const float4* X = (const float4*)(C + ((size_t)b * P_NODES + PAIRS.pj[p]) * DDIM);
        float part = 0.f;
        #pragma unroll
        for (int i = 0; i < 8; ++i) {
            int c = m + 4 * i;
            part += dot4(A[c], X[c]);
        }
        part += __shfl_xor(part, 1);
        part += __shfl_xor(part, 2);
        acc += lsig(part);                           // counted 4x (m duplicates)
    }
    acc += __shfl_xor(acc, 32);
    acc += __shfl_xor(acc, 16);
    acc += __shfl_xor(acc, 8);
    acc += __shfl_xor(acc, 4);
    acc += __shfl_xor(acc, 2);
    acc += __shfl_xor(acc, 1);
    if ((t & 63) == 0)
        atomicAdd(out, acc * (-1.f / (4.f * (float)BATCH)));
}

// ---- K2: one block per 64-row region; stream region into LDS, serve tasks ----
__global__ __launch_bounds__(256) void k_neg(
    const float* __restrict__ emb, const float* __restrict__ C,
    const int* __restrict__ cnt, const unsigned* __restrict__ rec,
    float* __restrict__ out)
{
    __shared__ float4 rows[BROWS * 32];              // 32 KB, slot rotated by row

    const int bucket = blockIdx.x;
    const int t      = threadIdx.x;
    const int base   = bucket * BROWS;

    // stream the region sequentially (coalesced 1KB/instr per wave)
    const float4* emb4 = (const float4*)emb;
    #pragma unroll
    for (int j = 0; j < 8; ++j) {
        int e = j * 256 + t;                         // 2048 float4s
        int r = e >> 5, c = e & 31;
        int gr = base + r;
        float4 v = (gr < N_TOTAL) ? emb4[(size_t)gr * 32 + c]
                                  : make_float4(0.f, 0.f, 0.f, 0.f);
        rows[r * 32 + ((c + r) & 31)] = v;
    }
    __syncthreads();

    const int count = min(cnt[bucket], CAP);
    const int l = t & 63;
    const int m = t & 3;
    const int quad = t >> 2;                         // 0..63 block-wide

    float acc = 0.f;
    for (int s = quad; s < count; s += 64) {
        unsigned rc = rec[(size_t)bucket * CAP + s];
        int lr  = (int)(rc & (BROWS - 1));
        int cid = (int)(rc >> 6);
        const float4* Crow = (const float4*)(C + (size_t)cid * DDIM);
        float part = 0.f;
        #pragma unroll
        for (int i = 0; i < 8; ++i) {
            int c = m + 4 * i;
            float4 nv = rows[lr * 32 + ((c + lr) & 31)];
            part += dot4(nv, Crow[c]);
        }
        part += __shfl_xor(part, 1);
        part += __shfl_xor(part, 2);
        acc += lsig(-part);                          // counted 4x
    }

    acc += __shfl_xor(acc, 32);
    acc += __shfl_xor(acc, 16);
    acc += __shfl_xor(acc, 8);
    acc += __shfl_xor(acc, 4);
    acc += __shfl_xor(acc, 2);
    acc += __shfl_xor(acc, 1);
    if (l == 0)
        atomicAdd(out, acc * (-1.f / (4.f * (float)BATCH)));
}

// ================= fallback (R4 kernel) if ws is too small =================
#define NTASK_F (N_PAIRS + N_NEG)
#define HALF_T  (NTASK_F / 2)

__global__ __launch_bounds__(256) void mp2v_fallback(
    const float* __restrict__ emb, const int* __restrict__ path,
    const int* __restrict__ neg, float* __restrict__ out)
{
    __shared__ float4 crow[P_NODES * 32];
    __shared__ int    nidx[N_NEG];
    __shared__ int    pidx[P_NODES];
    __shared__ unsigned char spi[N_PAIRS];
    __shared__ unsigned char spj[N_PAIRS];

    const int blk = blockIdx.x;
    const int b   = blk >> 1;
    const int q0  = (blk & 1) * HALF_T;
    const int q1  = q0 + HALF_T;
    const int t   = threadIdx.x;

    if (t < P_NODES) pidx[t] = path[b * P_NODES + t];
    if (t < N_PAIRS) { spi[t] = PAIRS.pi[t]; spj[t] = PAIRS.pj[t]; }
    for (int q = t; q < N_NEG; q += 256) {
        int p = (int)(((unsigned)q * 52429u) >> 18);
        int k = q - p * KNEG;
        nidx[q] = neg[(size_t)p * (BATCH * KNEG) + b * KNEG + k];
    }
    __syncthreads();
    for (int e = t; e < P_NODES * 32; e += 256) {
        int r = e >> 5, c = e & 31;
        float4 val = ((const float4*)(emb + (size_t)pidx[r] * DDIM))[c];
        crow[r * 32 + ((c + r) & 31)] = val;
    }
    __syncthreads();

    const int w = t >> 6, l = t & 63, r = l >> 2, m = l & 3;
    float acc = 0.f;
    for (int bse = q0 + w * 16; bse < q1; bse += 64) {
        int q = bse + r;
        if (q < q1) {
            float part = 0.f, sgn;
            if (q < N_PAIRS) {
                int ci = spi[q], cj = spj[q];
                #pragma unroll
                for (int i = 0; i < 8; ++i) {
                    int c = m + 4 * i;
                    part += dot4(crow[ci * 32 + ((c + ci) & 31)], crow[cj * 32 + ((c + cj) & 31)]);
                }
                sgn = 1.f;
            } else {
                int qq = q - N_PAIRS;
                int p  = (int)(((unsigned)qq * 52429u) >> 18);
                int ci = spi[p];
                const float4* R = (const float4*)(emb + (size_t)nidx[qq] * DDIM);
                #pragma unroll
                for (int i = 0; i < 8; ++i) {
                    int c = m + 4 * i;
                    part += dot4(R[c], crow[ci * 32 + ((c + ci) & 31)]);
                }
                sgn = -1.f;
            }
            part += __shfl_xor(part, 1);
            part += __shfl_xor(part, 2);
            acc += lsig(sgn * part);
        }
    }
    acc += __shfl_xor(acc, 32);
    acc += __shfl_xor(acc, 16);
    acc += __shfl_xor(acc, 8);
    acc += __shfl_xor(acc, 4);
    acc += __shfl_xor(acc, 2);
    acc += __shfl_xor(acc, 1);
    if (l == 0) atomicAdd(out, acc * (-1.f / (4.f * (float)BATCH)));
}

extern "C" void kernel_launch(void* const* d_in, const int* in_sizes, int n_in,
                              void* d_out, int out_size, void* d_ws, size_t ws_size,
                              hipStream_t stream) {
    const float* emb  = (const float*)d_in[0];
    const int*   path = (const int*)d_in[1];
    const int*   neg  = (const int*)d_in[2];
    float*       out  = (float*)d_out;

    hipMemsetAsync(out, 0, sizeof(float), stream);

    if (ws_size < WS_NEEDED) {
        mp2v_fallback<<<BATCH * 2, 256, 0, stream>>>(emb, path, neg, out);
        return;
    }

    char*     ws  = (char*)d_ws;
    float*    C   = (float*)ws;
    int*      cnt = (int*)(ws + CNT_OFF);
    unsigned* rec = (unsigned*)(ws + REC_OFF);

    hipMemsetAsync(cnt, 0, NBUCKET * sizeof(int), stream);

    k_build_c<<<(C_ROWS * DDIM) / 256, 256, 0, stream>>>(emb, path, C);
    k_bin<<<NNEG_TOT / 256, 256, 0, stream>>>(neg, cnt, rec);
    k_pos<<<740, 256, 0, stream>>>(C, out);
    k_neg<<<NBUCKET, 256, 0, stream>>>(emb, C, cnt, rec, out);
}

// Round 6
// 145.913 us; speedup vs baseline: 3.5767x; 3.5767x over previous
//
#include <hip/hip_runtime.h>
#include <math.h>

#define N_TOTAL 500000
#define P_NODES 21
#define KNEG    5
#define DDIM    128
#define BATCH   1024
#define N_PAIRS 185                  // pos tasks
#define N_NEG   (N_PAIRS * KNEG)     // 925 neg tasks
#define NTASK   (N_NEG + N_PAIRS)    // 1110 tasks per b: [0,925) neg, [925,1110) pos
#define HALF_T  (NTASK / 2)          // 555 per block, 2 blocks per b

struct Pairs { unsigned char pi[N_PAIRS]; unsigned char pj[N_PAIRS]; };

constexpr Pairs make_pairs() {
    Pairs p{};
    int n = 0;
    for (int i = 0; i < P_NODES; ++i) {
        int jlo = (i - KNEG > 0) ? i - KNEG : 0;
        int jhi = (i + KNEG < P_NODES) ? i + KNEG : P_NODES;
        for (int j = jlo; j < jhi; ++j) { p.pi[n] = (unsigned char)i; p.pj[n] = (unsigned char)j; ++n; }
    }
    return p;
}

__constant__ Pairs PAIRS = make_pairs();

// fast log-sigmoid: one v_exp + one v_log; dots are tiny here, no overflow risk.
__device__ __forceinline__ float lsig(float x) {
    return -__logf(1.f + __expf(-x));
}

__device__ __forceinline__ float dot4(float4 a, float4 b) {
    return fmaf(a.x, b.x, fmaf(a.y, b.y, fmaf(a.z, b.z, a.w * b.w)));
}

// 2 blocks per b, 256 threads. 8 lanes per dot-row (lane m owns cols m,m+8,m+16,m+24
// -> each instruction of a group = one full 128B line, fetched exactly once).
// Each group batches 4 tasks -> 16 independent global loads in flight per lane.
__global__ __launch_bounds__(256) void mp2v_kernel(
    const float* __restrict__ emb,
    const int*   __restrict__ path,
    const int*   __restrict__ neg,
    float*       __restrict__ out)
{
    __shared__ float4 crow[P_NODES * 32];     // 10.5 KB, slot rotated by row
    __shared__ int    nidx[N_NEG];            // 3.7 KB
    __shared__ int    pidx[P_NODES];
    __shared__ unsigned char spi[N_PAIRS];
    __shared__ unsigned char spj[N_PAIRS];

    const int blk = blockIdx.x;
    const int b   = blk >> 1;
    const int q0  = (blk & 1) * HALF_T;
    const int q1  = q0 + HALF_T;
    const int t   = threadIdx.x;

    // ---- stage indices ----
    if (t < P_NODES) pidx[t] = path[b * P_NODES + t];
    if (t < N_PAIRS) { spi[t] = PAIRS.pi[t]; spj[t] = PAIRS.pj[t]; }
    for (int q = t; q < N_NEG; q += 256) {
        int p = (int)(((unsigned)q * 52429u) >> 18);   // q/5 exact for q < 2^18
        int k = q - p * KNEG;
        nidx[q] = neg[(size_t)p * (BATCH * KNEG) + b * KNEG + k];
    }
    __syncthreads();   // pidx ready

    // ---- stage the 21 c-rows, rotated: row r float4-slot c -> slot (c+r)&31 ----
    for (int e = t; e < P_NODES * 32; e += 256) {
        int r = e >> 5, c = e & 31;
        float4 val = ((const float4*)(emb + (size_t)pidx[r] * DDIM))[c];
        crow[r * 32 + ((c + r) & 31)] = val;
    }
    __syncthreads();   // crow + nidx ready; no more barriers until the end

    const int g = t >> 3;          // group 0..31 (8 lanes per group)
    const int m = t & 7;           // float4 phase: cols m, m+8, m+16, m+24

    const float4* emb4 = (const float4*)emb;
    float acc = 0.f;

    for (int base = q0; base < q1; base += 128) {      // 5 iterations per block
        float4 rv[4][4];
        int    civ[4];
        float  sg[4];
        bool   val[4];

        // ---- load phase: 16 independent global (or LDS) reads ----
        #pragma unroll
        for (int k = 0; k < 4; ++k) {
            int qq = base + g * 4 + k;
            bool v = qq < q1;
            val[k] = v;
            int qc = v ? qq : q0;                      // q0 is always a neg task
            if (qc < N_NEG) {
                int p = (int)(((unsigned)qc * 52429u) >> 18);   // qc/5
                civ[k] = spi[p];
                sg[k]  = -1.f;
                const float4* R = emb4 + (size_t)nidx[qc] * 32;
                #pragma unroll
                for (int i = 0; i < 4; ++i) rv[k][i] = R[m + 8 * i];
            } else {
                int pp = qc - N_NEG;
                int cj = spj[pp];
                civ[k] = spi[pp];
                sg[k]  = 1.f;
                #pragma unroll
                for (int i = 0; i < 4; ++i) {
                    int c = m + 8 * i;
                    rv[k][i] = crow[cj * 32 + ((c + cj) & 31)];
                }
            }
        }

        // ---- compute phase ----
        #pragma unroll
        for (int k = 0; k < 4; ++k) {
            int ci = civ[k];
            float part = 0.f;
            #pragma unroll
            for (int i = 0; i < 4; ++i) {
                int c = m + 8 * i;
                part += dot4(rv[k][i], crow[ci * 32 + ((c + ci) & 31)]);
            }
            part += __shfl_xor(part, 1);
            part += __shfl_xor(part, 2);
            part += __shfl_xor(part, 4);
            if (val[k]) acc += lsig(sg[k] * part);     // counted 8x (m duplicates)
        }
    }

    // ---- wave reduce, one atomic per wave; 8x duplication scaled out ----
    acc += __shfl_xor(acc, 32);
    acc += __shfl_xor(acc, 16);
    acc += __shfl_xor(acc, 8);
    acc += __shfl_xor(acc, 4);
    acc += __shfl_xor(acc, 2);
    acc += __shfl_xor(acc, 1);
    if ((t & 63) == 0)
        atomicAdd(out, acc * (-1.f / (8.f * (float)BATCH)));
}

extern "C" void kernel_launch(void* const* d_in, const int* in_sizes, int n_in,
                              void* d_out, int out_size, void* d_ws, size_t ws_size,
                              hipStream_t stream) {
    const float* emb  = (const float*)d_in[0];
    const int*   path = (const int*)d_in[1];
    const int*   neg  = (const int*)d_in[2];
    float*       out  = (float*)d_out;

    // d_out is poisoned once before timing and never re-poisoned: zero it each call.
    hipMemsetAsync(out, 0, sizeof(float), stream);

    mp2v_kernel<<<BATCH * 2, 256, 0, stream>>>(emb, path, neg, out);
}